// Round 1
// baseline (133.826 us; speedup 1.0000x reference)
//
#include <hip/hip_runtime.h>

// VectorQuantizer: z [32,2048,64] f32, codebook [1024,64] f32.
// out = concat( z_q [4194304], c_loss [1], cb_loss [1] ); c_loss==cb_loss (BETA=1).
//
// R5 (this round), on top of R4's bf16-MFMA distance GEMM:
//  (a) vq_fin fused into vq_mfma via last-block atomic counter (-1 dispatch).
//  (b) packed argmin: dist' = 1 + ||c||^2 - 2 f.c  (strictly positive: |2 f.c| <=
//      2*64*max|z|*1.001e-3 ~ 0.71), low 10 mantissa bits replaced by code index.
//      Positive-float bits are order-monotonic, so v_min_f32 does the exact
//      (quantized-dist, k)-lexicographic min; 16-lane argmin butterfly becomes
//      1 shuffle + 1 min per step. Quantization ~1.2e-4 flips only near-ties
//      (bf16 already perturbs by ~4e-5); each flip bounded by 2e-3 << 2e-2.
//  (c) A fragments staged once through LDS (bit-identical; kills the 4x
//      redundant per-wave z load + bf16 convert). All LDS at 16B/lane stride
//      -> conflict-free.
// ~90 us of measured dur is harness ws re-poison fills (2 x 256 MiB); this
// round targets the ~16.6 us kernel-side budget.

#define VQ_NTOK   65536
#define VQ_D      64
#define VQ_K      1024
#define VQ_NELEM  (VQ_NTOK * VQ_D)
#define VQ_BLOCKS (VQ_NTOK / 64)

typedef short bf16x8 __attribute__((ext_vector_type(8)));
typedef float f32x4  __attribute__((ext_vector_type(4)));

#define WS_CSQ1      0        // 1024 floats: 1.0 + ||c_k||^2 (shift keeps dist' > 0)
#define WS_LOSS      1024     // float loss accumulator
#define WS_CTR       1025     // unsigned block-completion counter
#define WS_CBB_BYTES 8192     // 128 KB fragment-ordered bf16 codebook

__device__ __forceinline__ short bf16rn(float x) {   // round-to-nearest-even
    unsigned u = __builtin_bit_cast(unsigned, x);
    u += 0x7fffu + ((u >> 16) & 1u);
    return (short)(u >> 16);
}

// grid 32 x 256 = 8192 threads: csq1 + loss/ctr-zero + bf16 fragment codebook.
// Fragment order: element (chunk c, half h, lane L, j) = cb[c*16+(L&15)][h*32+(L>>4)*8+j]
__global__ __launch_bounds__(256) void vq_prep(const float* __restrict__ cb,
                                               float* __restrict__ ws) {
    int t = blockIdx.x * 256 + threadIdx.x;   // 0..8191
    if (t == 0) {                              // ws re-poisoned every launch
        ws[WS_LOSS] = 0.0f;
        ((unsigned*)ws)[WS_CTR] = 0u;
    }
    if (t < VQ_K) {
        const float4* row = (const float4*)(cb + t * VQ_D);
        float s = 1.0f;                        // fold the +1 positivity shift
        #pragma unroll
        for (int j = 0; j < 16; ++j) {
            float4 c = row[j];
            s += c.x * c.x + c.y * c.y + c.z * c.z + c.w * c.w;
        }
        ws[WS_CSQ1 + t] = s;
    }
    int c = t >> 7, h = (t >> 6) & 1, L = t & 63;
    int k  = c * 16 + (L & 15);
    int d0 = h * 32 + ((L >> 4) << 3);
    const float4* p = (const float4*)(cb + k * VQ_D + d0);
    float4 x0 = p[0], x1 = p[1];
    bf16x8 v;
    v[0] = bf16rn(x0.x); v[1] = bf16rn(x0.y); v[2] = bf16rn(x0.z); v[3] = bf16rn(x0.w);
    v[4] = bf16rn(x1.x); v[5] = bf16rn(x1.y); v[6] = bf16rn(x1.z); v[7] = bf16rn(x1.w);
    bf16x8* cbb = (bf16x8*)((char*)ws + WS_CBB_BYTES);
    cbb[(c * 2 + h) * 64 + L] = v;
}

__global__ __launch_bounds__(256, 4) void vq_mfma(
        const float* __restrict__ z, const float* __restrict__ cb,
        float* __restrict__ ws, float* __restrict__ out) {
    const int tid  = threadIdx.x;
    const int lane = tid & 63;
    const int wave = tid >> 6;         // k-split: wave w scans codes [w*256,(w+1)*256)
    const int m    = lane & 15;        // MFMA col (code) in C/D
    const int q    = lane >> 4;        // quad
    const int tokbase = blockIdx.x << 6;

    __shared__ bf16x8 s_a[8][64];      // A fragments [t*2+h][lane], 8 KB
    __shared__ float  s_b[4][64];      // per-wave packed winner per token
    __shared__ float  s_loss[4];

    // Stage A fragments ONCE (R4 had each wave redundantly load+convert all 64
    // tokens). Thread handles fragment slots (g, L) and (g+4, L); LDS writes and
    // reads are lane*16B contiguous -> conflict-free ds_*_b128.
    {
        const int L = tid & 63;
        #pragma unroll
        for (int gi = 0; gi < 2; ++gi) {
            const int g = (tid >> 6) + gi * 4;          // 0..7
            const int t = g >> 1, h = g & 1;
            const int tok = t * 16 + (L & 15);
            const int d0  = h * 32 + ((L >> 4) << 3);
            const float4* p = (const float4*)(z + (size_t)(tokbase + tok) * VQ_D + d0);
            float4 x0 = p[0], x1 = p[1];
            bf16x8 v;
            v[0] = bf16rn(x0.x); v[1] = bf16rn(x0.y); v[2] = bf16rn(x0.z); v[3] = bf16rn(x0.w);
            v[4] = bf16rn(x1.x); v[5] = bf16rn(x1.y); v[6] = bf16rn(x1.z); v[7] = bf16rn(x1.w);
            s_a[g][L] = v;
        }
    }
    __syncthreads();

    bf16x8 aA[4][2];
    #pragma unroll
    for (int t = 0; t < 4; ++t) {
        aA[t][0] = s_a[t * 2 + 0][lane];
        aA[t][1] = s_a[t * 2 + 1][lane];
    }

    const bf16x8* cbb  = (const bf16x8*)((const char*)ws + WS_CBB_BYTES);
    const float*  csq1 = ws + WS_CSQ1;

    // Packed running min: float bits = quantized dist' (top 22) | code k (low 10).
    float bestp[4][4];
    #pragma unroll
    for (int t = 0; t < 4; ++t)
        #pragma unroll
        for (int r = 0; r < 4; ++r) bestp[t][r] = 3.4e38f;

    const int c0 = wave << 4;          // 16 chunks of 16 codes
    for (int cc = 0; cc < 16; ++cc) {
        const int c = c0 + cc;
        bf16x8 b0 = cbb[(c * 2 + 0) * 64 + lane];   // contiguous 1KB/wave, L2-hot
        bf16x8 b1 = cbb[(c * 2 + 1) * 64 + lane];
        const float    cs1 = csq1[(c << 4) + m];    // 1 + ||c||^2
        const unsigned kc  = (unsigned)((c << 4) + m);
        #pragma unroll
        for (int t = 0; t < 4; ++t) {
            f32x4 acc = {0.f, 0.f, 0.f, 0.f};
            acc = __builtin_amdgcn_mfma_f32_16x16x32_bf16(aA[t][0], b0, acc, 0, 0, 0);
            acc = __builtin_amdgcn_mfma_f32_16x16x32_bf16(aA[t][1], b1, acc, 0, 0, 0);
            #pragma unroll
            for (int r = 0; r < 4; ++r) {           // C/D: col=m (code), row=q*4+r (token)
                float d = fmaf(-2.0f, acc[r], cs1); // dist' in [~0.29, ~1.3] > 0
                unsigned pb = (__builtin_bit_cast(unsigned, d) & 0xFFFFFC00u) | kc;
                bestp[t][r] = fminf(bestp[t][r], __builtin_bit_cast(float, pb));
            }
        }
    }

    // Cross-lane argmin over the 16 col-lanes: packed min IS the lexicographic
    // (dist, k) combine -> 1 shuffle + 1 v_min_f32 per step.
    #pragma unroll
    for (int t = 0; t < 4; ++t) {
        #pragma unroll
        for (int r = 0; r < 4; ++r) {
            float v = bestp[t][r];
            #pragma unroll
            for (int off = 1; off < 16; off <<= 1)
                v = fminf(v, __shfl_xor(v, off));
            if (m == 0) s_b[wave][t * 16 + q * 4 + r] = v;
        }
    }
    __syncthreads();

    // Epilogue: thread -> (token, quarter-row). Wave chunks have disjoint
    // ascending code ranges; packed min preserves the first-min tie rule.
    const int tok = tid >> 2, part = tid & 3;
    float pv = fminf(fminf(s_b[0][tok], s_b[1][tok]),
                     fminf(s_b[2][tok], s_b[3][tok]));
    const int bk = (int)(__builtin_bit_cast(unsigned, pv) & 1023u);
    const float4* crow = (const float4*)(cb + (size_t)bk * VQ_D + part * 16);
    const float4* zrow = (const float4*)(z + (size_t)(tokbase + tok) * VQ_D + part * 16);
    float4*       orow = (float4*)(out + (size_t)(tokbase + tok) * VQ_D + part * 16);
    float lsum = 0.f;
    #pragma unroll
    for (int j = 0; j < 4; ++j) {
        float4 cv = crow[j], zv = zrow[j];
        orow[j] = cv;
        float e0 = zv.x - cv.x, e1 = zv.y - cv.y;
        float e2 = zv.z - cv.z, e3 = zv.w - cv.w;
        lsum += e0 * e0 + e1 * e1 + e2 * e2 + e3 * e3;
    }
    #pragma unroll
    for (int off = 32; off > 0; off >>= 1) lsum += __shfl_down(lsum, off);
    if (lane == 0) s_loss[wave] = lsum;
    __syncthreads();

    // Fused finalize: last block to retire publishes the losses.
    if (tid == 0) {
        atomicAdd(ws + WS_LOSS, s_loss[0] + s_loss[1] + s_loss[2] + s_loss[3]);
        __threadfence();                                   // loss-add visible before ctr
        unsigned done = atomicAdd((unsigned*)ws + WS_CTR, 1u);
        if (done == VQ_BLOCKS - 1) {
            float tot = atomicAdd(ws + WS_LOSS, 0.0f);     // device-coherent read
            float msq = tot * (1.0f / (float)VQ_NELEM);
            out[VQ_NELEM]     = msq;   // c_loss  (BETA = 1.0)
            out[VQ_NELEM + 1] = msq;   // cb_loss
        }
    }
}

extern "C" void kernel_launch(void* const* d_in, const int* in_sizes, int n_in,
                              void* d_out, int out_size, void* d_ws, size_t ws_size,
                              hipStream_t stream) {
    const float* z  = (const float*)d_in[0];
    const float* cb = (const float*)d_in[1];
    float* out = (float*)d_out;
    float* ws  = (float*)d_ws;

    vq_prep<<<dim3(32), dim3(256), 0, stream>>>(cb, ws);
    vq_mfma<<<dim3(VQ_BLOCKS), dim3(256), 0, stream>>>(z, cb, ws, out);
}

// Round 2
// 100.733 us; speedup vs baseline: 1.3285x; 1.3285x over previous
//
#include <hip/hip_runtime.h>

// VectorQuantizer: z [32,2048,64] f32, codebook [1024,64] f32.
// out = concat( z_q [4194304], c_loss [1], cb_loss [1] ); c_loss==cb_loss (BETA=1).
//
// R6: revert R5's fused finalize. The per-block __threadfence() (device-scope
// fence -> L2 writeback on CDNA) + second same-line atomic stalled vq_mfma
// 80us idle (MfmaUtil 4%, VALUBusy 14%, HBM 1.5%). Finalize is again a
// separate 1-thread kernel reading the relaxed atomicAdd total (R4 scheme,
// proven <43us for vq_mfma). Kept from R5 (both verified, absmax 1.95e-3):
//  (b) packed argmin: dist' = 1 + ||c||^2 - 2 f.c (strictly positive: |2 f.c|
//      <= 2*64*max|z|*1.001e-3 ~ 0.71); low 10 mantissa bits replaced by code
//      index. Positive-float bits are order-monotonic, so v_min_f32 performs
//      the exact (quantized-dist, k)-lexicographic min; the 16-lane argmin
//      butterfly is 1 shuffle + 1 min per step. Quantization ~1.2e-4 flips
//      only near-ties (bf16 already perturbs ~4e-5); each flip bounded by
//      codebook diameter 2e-3 << 2e-2 threshold.
//  (c) A fragments staged once through LDS (kills the 4x redundant per-wave
//      z load + bf16 convert). All LDS at 16B/lane stride -> conflict-free.
// ~90us of measured dur is harness ws re-poison fills (2 x 256MiB); the
// controllable kernel-side budget is ~16us.

#define VQ_NTOK   65536
#define VQ_D      64
#define VQ_K      1024
#define VQ_NELEM  (VQ_NTOK * VQ_D)
#define VQ_BLOCKS (VQ_NTOK / 64)

typedef short bf16x8 __attribute__((ext_vector_type(8)));
typedef float f32x4  __attribute__((ext_vector_type(4)));

#define WS_CSQ1      0        // 1024 floats: 1.0 + ||c_k||^2 (shift keeps dist' > 0)
#define WS_LOSS      1024     // float loss accumulator
#define WS_CBB_BYTES 8192     // 128 KB fragment-ordered bf16 codebook

__device__ __forceinline__ short bf16rn(float x) {   // round-to-nearest-even
    unsigned u = __builtin_bit_cast(unsigned, x);
    u += 0x7fffu + ((u >> 16) & 1u);
    return (short)(u >> 16);
}

// grid 32 x 256 = 8192 threads: csq1 + loss-zero + bf16 fragment codebook.
// Fragment order: element (chunk c, half h, lane L, j) = cb[c*16+(L&15)][h*32+(L>>4)*8+j]
__global__ __launch_bounds__(256) void vq_prep(const float* __restrict__ cb,
                                               float* __restrict__ ws) {
    int t = blockIdx.x * 256 + threadIdx.x;   // 0..8191
    if (t == 0) ws[WS_LOSS] = 0.0f;           // ws re-poisoned every launch
    if (t < VQ_K) {
        const float4* row = (const float4*)(cb + t * VQ_D);
        float s = 1.0f;                        // fold the +1 positivity shift
        #pragma unroll
        for (int j = 0; j < 16; ++j) {
            float4 c = row[j];
            s += c.x * c.x + c.y * c.y + c.z * c.z + c.w * c.w;
        }
        ws[WS_CSQ1 + t] = s;
    }
    int c = t >> 7, h = (t >> 6) & 1, L = t & 63;
    int k  = c * 16 + (L & 15);
    int d0 = h * 32 + ((L >> 4) << 3);
    const float4* p = (const float4*)(cb + k * VQ_D + d0);
    float4 x0 = p[0], x1 = p[1];
    bf16x8 v;
    v[0] = bf16rn(x0.x); v[1] = bf16rn(x0.y); v[2] = bf16rn(x0.z); v[3] = bf16rn(x0.w);
    v[4] = bf16rn(x1.x); v[5] = bf16rn(x1.y); v[6] = bf16rn(x1.z); v[7] = bf16rn(x1.w);
    bf16x8* cbb = (bf16x8*)((char*)ws + WS_CBB_BYTES);
    cbb[(c * 2 + h) * 64 + L] = v;
}

__global__ __launch_bounds__(256, 4) void vq_mfma(
        const float* __restrict__ z, const float* __restrict__ cb,
        float* __restrict__ ws, float* __restrict__ out) {
    const int tid  = threadIdx.x;
    const int lane = tid & 63;
    const int wave = tid >> 6;         // k-split: wave w scans codes [w*256,(w+1)*256)
    const int m    = lane & 15;        // MFMA col (code) in C/D
    const int q    = lane >> 4;        // quad
    const int tokbase = blockIdx.x << 6;

    __shared__ bf16x8 s_a[8][64];      // A fragments [t*2+h][lane], 8 KB
    __shared__ float  s_b[4][64];      // per-wave packed winner per token
    __shared__ float  s_loss[4];

    // Stage A fragments ONCE. Thread handles fragment slots (wave, L) and
    // (wave+4, L); LDS writes/reads are lane*16B contiguous -> conflict-free.
    {
        const int L = tid & 63;
        #pragma unroll
        for (int gi = 0; gi < 2; ++gi) {
            const int g = (tid >> 6) + gi * 4;          // 0..7
            const int t = g >> 1, h = g & 1;
            const int tok = t * 16 + (L & 15);
            const int d0  = h * 32 + ((L >> 4) << 3);
            const float4* p = (const float4*)(z + (size_t)(tokbase + tok) * VQ_D + d0);
            float4 x0 = p[0], x1 = p[1];
            bf16x8 v;
            v[0] = bf16rn(x0.x); v[1] = bf16rn(x0.y); v[2] = bf16rn(x0.z); v[3] = bf16rn(x0.w);
            v[4] = bf16rn(x1.x); v[5] = bf16rn(x1.y); v[6] = bf16rn(x1.z); v[7] = bf16rn(x1.w);
            s_a[g][L] = v;
        }
    }
    __syncthreads();

    bf16x8 aA[4][2];
    #pragma unroll
    for (int t = 0; t < 4; ++t) {
        aA[t][0] = s_a[t * 2 + 0][lane];
        aA[t][1] = s_a[t * 2 + 1][lane];
    }

    const bf16x8* cbb  = (const bf16x8*)((const char*)ws + WS_CBB_BYTES);
    const float*  csq1 = ws + WS_CSQ1;

    // Packed running min: float bits = quantized dist' (top 22) | code k (low 10).
    float bestp[4][4];
    #pragma unroll
    for (int t = 0; t < 4; ++t)
        #pragma unroll
        for (int r = 0; r < 4; ++r) bestp[t][r] = 3.4e38f;

    const int c0 = wave << 4;          // 16 chunks of 16 codes
    for (int cc = 0; cc < 16; ++cc) {
        const int c = c0 + cc;
        bf16x8 b0 = cbb[(c * 2 + 0) * 64 + lane];   // contiguous 1KB/wave, L2-hot
        bf16x8 b1 = cbb[(c * 2 + 1) * 64 + lane];
        const float    cs1 = csq1[(c << 4) + m];    // 1 + ||c||^2
        const unsigned kc  = (unsigned)((c << 4) + m);
        #pragma unroll
        for (int t = 0; t < 4; ++t) {
            f32x4 acc = {0.f, 0.f, 0.f, 0.f};
            acc = __builtin_amdgcn_mfma_f32_16x16x32_bf16(aA[t][0], b0, acc, 0, 0, 0);
            acc = __builtin_amdgcn_mfma_f32_16x16x32_bf16(aA[t][1], b1, acc, 0, 0, 0);
            #pragma unroll
            for (int r = 0; r < 4; ++r) {           // C/D: col=m (code), row=q*4+r (token)
                float d = fmaf(-2.0f, acc[r], cs1); // dist' in [~0.29, ~1.3] > 0
                unsigned pb = (__builtin_bit_cast(unsigned, d) & 0xFFFFFC00u) | kc;
                bestp[t][r] = fminf(bestp[t][r], __builtin_bit_cast(float, pb));
            }
        }
    }

    // Cross-lane argmin over the 16 col-lanes: packed min IS the lexicographic
    // (dist, k) combine -> 1 shuffle + 1 v_min_f32 per step.
    #pragma unroll
    for (int t = 0; t < 4; ++t) {
        #pragma unroll
        for (int r = 0; r < 4; ++r) {
            float v = bestp[t][r];
            #pragma unroll
            for (int off = 1; off < 16; off <<= 1)
                v = fminf(v, __shfl_xor(v, off));
            if (m == 0) s_b[wave][t * 16 + q * 4 + r] = v;
        }
    }
    __syncthreads();

    // Epilogue: thread -> (token, quarter-row). Wave chunks have disjoint
    // ascending code ranges; packed min preserves the first-min tie rule.
    const int tok = tid >> 2, part = tid & 3;
    float pv = fminf(fminf(s_b[0][tok], s_b[1][tok]),
                     fminf(s_b[2][tok], s_b[3][tok]));
    const int bk = (int)(__builtin_bit_cast(unsigned, pv) & 1023u);
    const float4* crow = (const float4*)(cb + (size_t)bk * VQ_D + part * 16);
    const float4* zrow = (const float4*)(z + (size_t)(tokbase + tok) * VQ_D + part * 16);
    float4*       orow = (float4*)(out + (size_t)(tokbase + tok) * VQ_D + part * 16);
    float lsum = 0.f;
    #pragma unroll
    for (int j = 0; j < 4; ++j) {
        float4 cv = crow[j], zv = zrow[j];
        orow[j] = cv;
        float e0 = zv.x - cv.x, e1 = zv.y - cv.y;
        float e2 = zv.z - cv.z, e3 = zv.w - cv.w;
        lsum += e0 * e0 + e1 * e1 + e2 * e2 + e3 * e3;
    }
    #pragma unroll
    for (int off = 32; off > 0; off >>= 1) lsum += __shfl_down(lsum, off);
    if (lane == 0) s_loss[wave] = lsum;
    __syncthreads();
    if (tid == 0)
        atomicAdd(ws + WS_LOSS, s_loss[0] + s_loss[1] + s_loss[2] + s_loss[3]);
}

__global__ void vq_fin(const float* __restrict__ ws, float* __restrict__ out) {
    if (threadIdx.x == 0 && blockIdx.x == 0) {
        float msq = ws[WS_LOSS] * (1.0f / (float)VQ_NELEM);
        out[VQ_NELEM]     = msq;   // c_loss  (BETA = 1.0)
        out[VQ_NELEM + 1] = msq;   // cb_loss
    }
}

extern "C" void kernel_launch(void* const* d_in, const int* in_sizes, int n_in,
                              void* d_out, int out_size, void* d_ws, size_t ws_size,
                              hipStream_t stream) {
    const float* z  = (const float*)d_in[0];
    const float* cb = (const float*)d_in[1];
    float* out = (float*)d_out;
    float* ws  = (float*)d_ws;

    vq_prep<<<dim3(32), dim3(256), 0, stream>>>(cb, ws);
    vq_mfma<<<dim3(VQ_BLOCKS), dim3(256), 0, stream>>>(z, cb, ws, out);
    vq_fin<<<dim3(1), dim3(64), 0, stream>>>(ws, out);
}